// Round 1
// baseline (5017.332 us; speedup 1.0000x reference)
//
#include <hip/hip_runtime.h>

#define DI __device__ __forceinline__

DI float frcp(float x) {
    float r;
    asm("v_rcp_f32 %0, %1" : "=v"(r) : "v"(x));
    return r;
}
DI float fsig(float x) {
    // 1/(1+e^-x); saturates correctly at +-inf
    return frcp(1.0f + __expf(-x));
}
DI float ftanh(float x) {
    // 1 - 2/(1+e^{2x}); exact at +-inf
    return 1.0f - 2.0f * frcp(1.0f + __expf(2.0f * x));
}

// ---------------- conv 7x7 masked, 1 -> 16 ch, pad 3 ----------------
__global__ __launch_bounds__(256) void k_conv(const float* __restrict__ X,
                                              const float* __restrict__ Wc,
                                              const float* __restrict__ Bc,
                                              float* __restrict__ xo) {
    int n = blockIdx.x * 256 + threadIdx.x;
    int xx = n & 63, yy = (n >> 6) & 63, b = n >> 12;
    float acc[16];
#pragma unroll
    for (int o = 0; o < 16; ++o) acc[o] = Bc[o];
    const float* Xb = X + (size_t)b * 4096;
#pragma unroll
    for (int ky = 0; ky < 4; ++ky) {
        int yi = yy + ky - 3;
        if (yi < 0) continue;
        int kxmax = (ky == 3) ? 3 : 7;
        for (int kx = 0; kx < kxmax; ++kx) {
            int xi = xx + kx - 3;
            if (xi < 0 || xi > 63) continue;
            float v = Xb[yi * 64 + xi];
#pragma unroll
            for (int o = 0; o < 16; ++o)
                acc[o] = fmaf(Wc[o * 49 + ky * 7 + kx], v, acc[o]);
        }
    }
#pragma unroll
    for (int o = 0; o < 16; ++o)
        xo[(((size_t)b * 16 + o) * 64 + yy) * 64 + xx] = acc[o];
}

// ---------------- prep: residual combine + i2s GEMM into G ----------------
// x layout: NCHW [b][c][r][w]
// fwd/bwd layout: [b][r][w][c]  (bwd holds the un-reversed bwd output)
// G layout (float): [dir][b][r][w][g]  (for bwd dir, w is the REVERSED coord)
__global__ __launch_bounds__(256) void k_prep(float* __restrict__ x,
                                              const float* __restrict__ fwd,
                                              const float* __restrict__ bwdr,
                                              const float* __restrict__ wi_all,
                                              int layer, int addflag,
                                              float* __restrict__ G) {
    __shared__ float wsh[2048];  // [dir][g][c]
    for (int i = threadIdx.x; i < 2048; i += 256)
        wsh[i] = wi_all[layer * 2048 + i];
    __syncthreads();

    int n = blockIdx.x * 256 + threadIdx.x;
    int w = n & 63, r = (n >> 6) & 63, b = n >> 12;

    float v[16];
#pragma unroll
    for (int c = 0; c < 16; ++c)
        v[c] = x[(((size_t)b * 16 + c) * 64 + r) * 64 + w];
    if (addflag) {
        const float* fp = fwd + (((size_t)b * 64 + r) * 64 + w) * 16;
#pragma unroll
        for (int c = 0; c < 16; ++c) v[c] += fp[c];
        if (r > 0) {
            const float* bp = bwdr + (((size_t)b * 64 + (r - 1)) * 64 + w) * 16;
#pragma unroll
            for (int c = 0; c < 16; ++c) v[c] += bp[c];
        }
#pragma unroll
        for (int c = 0; c < 16; ++c)
            x[(((size_t)b * 16 + c) * 64 + r) * 64 + w] = v[c];
    }

    const float4* wf4 = reinterpret_cast<const float4*>(wsh);
    const float4* wb4 = reinterpret_cast<const float4*>(wsh + 1024);
    float4* Gf = reinterpret_cast<float4*>(G + ((((size_t)b * 64 + r) * 64 + w) << 6));
    float4* Gb = reinterpret_cast<float4*>(G + (((((size_t)32 + b) * 64 + r) * 64 + (63 - w)) << 6));

    float4 accf, accb;
#pragma unroll
    for (int g = 0; g < 64; ++g) {
        float af = 0.f, ab = 0.f;
#pragma unroll
        for (int c4 = 0; c4 < 4; ++c4) {
            float4 a = wf4[g * 4 + c4];
            float4 bq = wb4[g * 4 + c4];
            af = fmaf(a.x, v[c4 * 4 + 0], af);
            af = fmaf(a.y, v[c4 * 4 + 1], af);
            af = fmaf(a.z, v[c4 * 4 + 2], af);
            af = fmaf(a.w, v[c4 * 4 + 3], af);
            ab = fmaf(bq.x, v[c4 * 4 + 0], ab);
            ab = fmaf(bq.y, v[c4 * 4 + 1], ab);
            ab = fmaf(bq.z, v[c4 * 4 + 2], ab);
            ab = fmaf(bq.w, v[c4 * 4 + 3], ab);
        }
        int m = g & 3;
        if (m == 0) { accf.x = af; accb.x = ab; }
        else if (m == 1) { accf.y = af; accb.y = ab; }
        else if (m == 2) { accf.z = af; accb.z = ab; }
        else {
            accf.w = af; accb.w = ab;
            Gf[g >> 2] = accf;
            Gb[g >> 2] = accb;
        }
    }
}

// ---------------- diagonal LSTM scan: one block per (b,dir) ----------------
// 512 threads: phase A thread (gq=t&15 -> 4 gates, rp=t>>4 -> rows 2rp,2rp+1)
//              phase B thread (ch=t&15, same row pair), c-state in registers.
__global__ __launch_bounds__(512, 2) void k_scan(const float* __restrict__ G,
                                                 const float* __restrict__ w0_all,
                                                 const float* __restrict__ w1_all,
                                                 const float* __restrict__ bi_all,
                                                 int layer,
                                                 float* __restrict__ fwdbuf,
                                                 float* __restrict__ bwdbuf) {
    int dir = blockIdx.x >> 5, b = blockIdx.x & 31;
    int t = threadIdx.x;
    int gq = t & 15, rp = t >> 4;
    int g0 = gq * 4, r0 = rp * 2;
    int wbase = (layer * 2 + dir) * 1024;

    float w1r[4][16], w0r[4][16], bir[4];
#pragma unroll
    for (int j = 0; j < 4; ++j) {
#pragma unroll
        for (int c = 0; c < 16; ++c) {
            w1r[j][c] = w1_all[wbase + (g0 + j) * 16 + c];
            w0r[j][c] = w0_all[wbase + (g0 + j) * 16 + c];
        }
        bir[j] = bi_all[(layer * 2 + dir) * 64 + g0 + j];
    }

    __shared__ float h_lds[16 * 65 + 1];  // h_lds[c*65 + 1 + r], guard row at +0
    __shared__ float s_lds[64 * 65];      // s_lds[g*65 + r]
    for (int i = t; i < 16 * 65 + 1; i += 512) h_lds[i] = 0.f;

    int ch = gq;
    float cst0 = 0.f, cst1 = 0.f;
    const float* Gb = G + ((size_t)(dir * 32 + b) << 18);
    float* ob = dir ? bwdbuf : fwdbuf;
    size_t obase = (size_t)b * 65536;
    __syncthreads();

#pragma unroll 1
    for (int tt = 0; tt < 127; ++tt) {
        // ---- phase A: s = bi + W1 h + W0 h_up (+ G where valid) ----
        float g4[2][4];
#pragma unroll
        for (int d = 0; d < 2; ++d) {
            int r = r0 + d, w = tt - r;
            if (w >= 0 && w < 64) {
                float4 gv = *reinterpret_cast<const float4*>(Gb + (((r << 6) + w) << 6) + g0);
                g4[d][0] = gv.x; g4[d][1] = gv.y; g4[d][2] = gv.z; g4[d][3] = gv.w;
            } else {
                g4[d][0] = g4[d][1] = g4[d][2] = g4[d][3] = 0.f;
            }
        }
        float s[4][2];
#pragma unroll
        for (int j = 0; j < 4; ++j) { s[j][0] = bir[j]; s[j][1] = bir[j]; }
#pragma unroll
        for (int c = 0; c < 16; ++c) {
            float hm = h_lds[c * 65 + r0];       // h[r0-1] (guard -> 0)
            float h0 = h_lds[c * 65 + 1 + r0];   // h[r0]
            float h1 = h_lds[c * 65 + 2 + r0];   // h[r0+1]
#pragma unroll
            for (int j = 0; j < 4; ++j) {
                s[j][0] = fmaf(w1r[j][c], h0, s[j][0]);
                s[j][0] = fmaf(w0r[j][c], hm, s[j][0]);
                s[j][1] = fmaf(w1r[j][c], h1, s[j][1]);
                s[j][1] = fmaf(w0r[j][c], h0, s[j][1]);
            }
        }
#pragma unroll
        for (int j = 0; j < 4; ++j) {
            s_lds[(g0 + j) * 65 + r0] = s[j][0] + g4[0][j];
            s_lds[(g0 + j) * 65 + r0 + 1] = s[j][1] + g4[1][j];
        }
        __syncthreads();

        // ---- phase B: gates, state update, h write ----
#pragma unroll
        for (int d = 0; d < 2; ++d) {
            int r = r0 + d;
            float so = s_lds[ch * 65 + r];
            float sf = s_lds[(ch + 16) * 65 + r];
            float si = s_lds[(ch + 32) * 65 + r];
            float sg = s_lds[(ch + 48) * 65 + r];
            float cs = d ? cst1 : cst0;
            float cn = fsig(sf) * cs + fsig(si) * ftanh(sg);
            if (d) cst1 = cn; else cst0 = cn;
            float hn = fsig(so) * ftanh(cn);
            h_lds[ch * 65 + 1 + r] = hn;
            int w = tt - r;
            if (w >= 0 && w < 64) {
                int wo = dir ? (63 - w) : w;
                ob[obase + ((size_t)((r << 6) + wo) << 4) + ch] = hn;
            }
        }
        __syncthreads();
    }
}

// ---------------- head: residual combine + 3-layer MLP ----------------
__global__ __launch_bounds__(256) void k_head(const float* __restrict__ x,
                                              const float* __restrict__ fwd,
                                              const float* __restrict__ bwdr,
                                              const float* __restrict__ W1,
                                              const float* __restrict__ B1,
                                              const float* __restrict__ W2,
                                              const float* __restrict__ B2,
                                              const float* __restrict__ W3,
                                              const float* __restrict__ B3,
                                              float* __restrict__ out) {
    int n = blockIdx.x * 256 + threadIdx.x;
    int w = n & 63, r = (n >> 6) & 63, b = n >> 12;
    float v[16];
    const float* fp = fwd + (((size_t)b * 64 + r) * 64 + w) * 16;
#pragma unroll
    for (int c = 0; c < 16; ++c)
        v[c] = x[(((size_t)b * 16 + c) * 64 + r) * 64 + w] + fp[c];
    if (r > 0) {
        const float* bp = bwdr + (((size_t)b * 64 + (r - 1)) * 64 + w) * 16;
#pragma unroll
        for (int c = 0; c < 16; ++c) v[c] += bp[c];
    }
    float h1[16];
#pragma unroll
    for (int o = 0; o < 16; ++o) {
        float a = B1[o];
#pragma unroll
        for (int c = 0; c < 16; ++c) a = fmaf(W1[o * 16 + c], v[c], a);
        h1[o] = fmaxf(a, 0.f);
    }
    float h2[16];
#pragma unroll
    for (int o = 0; o < 16; ++o) {
        float a = B2[o];
#pragma unroll
        for (int c = 0; c < 16; ++c) a = fmaf(W2[o * 16 + c], h1[c], a);
        h2[o] = fmaxf(a, 0.f);
    }
    float y = B3[0];
#pragma unroll
    for (int c = 0; c < 16; ++c) y = fmaf(W3[c], h2[c], y);
    out[((size_t)b * 64 + r) * 64 + w] = y;
}

extern "C" void kernel_launch(void* const* d_in, const int* in_sizes, int n_in,
                              void* d_out, int out_size, void* d_ws, size_t ws_size,
                              hipStream_t stream) {
    const float* X  = (const float*)d_in[0];
    const float* cw = (const float*)d_in[1];
    const float* cb = (const float*)d_in[2];
    const float* wi = (const float*)d_in[3];
    const float* bi = (const float*)d_in[4];
    const float* w0 = (const float*)d_in[5];
    const float* w1 = (const float*)d_in[6];
    const float* W1 = (const float*)d_in[7];
    const float* B1 = (const float*)d_in[8];
    const float* W2 = (const float*)d_in[9];
    const float* B2 = (const float*)d_in[10];
    const float* W3 = (const float*)d_in[11];
    const float* B3 = (const float*)d_in[12];
    float* out = (float*)d_out;

    char* ws = (char*)d_ws;
    float* x   = (float*)ws;                          //  8 MiB (32*16*64*64)
    float* fwd = (float*)(ws + ((size_t)8 << 20));    //  8 MiB
    float* bwd = (float*)(ws + ((size_t)16 << 20));   //  8 MiB
    float* G   = (float*)(ws + ((size_t)24 << 20));   // 64 MiB (2*32*64*64*64)

    k_conv<<<512, 256, 0, stream>>>(X, cw, cb, x);
    for (int l = 0; l < 7; ++l) {
        k_prep<<<512, 256, 0, stream>>>(x, fwd, bwd, wi, l, l > 0 ? 1 : 0, G);
        k_scan<<<64, 512, 0, stream>>>(G, w0, w1, bi, l, fwd, bwd);
    }
    k_head<<<512, 256, 0, stream>>>(x, fwd, bwd, W1, B1, W2, B2, W3, B3, out);
}

// Round 2
// 1664.783 us; speedup vs baseline: 3.0138x; 3.0138x over previous
//
#include <hip/hip_runtime.h>

#define DI __device__ __forceinline__

DI float frcp(float x) { return __builtin_amdgcn_rcpf(x); }
DI float fsig(float x) {
    return frcp(1.0f + __expf(-x));
}
DI float ftanh(float x) {
    return 1.0f - 2.0f * frcp(1.0f + __expf(2.0f * x));
}

// ---------------- conv 7x7 masked, 1 -> 16 ch, pad 3 ----------------
__global__ __launch_bounds__(256) void k_conv(const float* __restrict__ X,
                                              const float* __restrict__ Wc,
                                              const float* __restrict__ Bc,
                                              float* __restrict__ xo) {
    int n = blockIdx.x * 256 + threadIdx.x;
    int xx = n & 63, yy = (n >> 6) & 63, b = n >> 12;
    float acc[16];
#pragma unroll
    for (int o = 0; o < 16; ++o) acc[o] = Bc[o];
    const float* Xb = X + (size_t)b * 4096;
#pragma unroll
    for (int ky = 0; ky < 4; ++ky) {
        int yi = yy + ky - 3;
        if (yi < 0) continue;
        int kxmax = (ky == 3) ? 3 : 7;
        for (int kx = 0; kx < kxmax; ++kx) {
            int xi = xx + kx - 3;
            if (xi < 0 || xi > 63) continue;
            float v = Xb[yi * 64 + xi];
#pragma unroll
            for (int o = 0; o < 16; ++o)
                acc[o] = fmaf(Wc[o * 49 + ky * 7 + kx], v, acc[o]);
        }
    }
#pragma unroll
    for (int o = 0; o < 16; ++o)
        xo[(((size_t)b * 16 + o) * 64 + yy) * 64 + xx] = acc[o];
}

// ---------------- prep: residual combine + i2s GEMV into G ----------------
// x layout: NCHW [b][c][r][w]
// fwd/bwd layout: [b][r][w][c]  (bwd holds the un-reversed bwd output)
// G layout (float): [dir][b][r][w][ch*4 + k] where gate index = 16*k + ch
//   (for bwd dir, w is the REVERSED coord)
__global__ __launch_bounds__(256) void k_prep(float* __restrict__ x,
                                              const float* __restrict__ fwd,
                                              const float* __restrict__ bwdr,
                                              const float* __restrict__ wi_all,
                                              int layer, int addflag,
                                              float* __restrict__ G) {
    __shared__ float wsh[2048];  // [dir][g][c]
    for (int i = threadIdx.x; i < 2048; i += 256)
        wsh[i] = wi_all[layer * 2048 + i];
    __syncthreads();

    int n = blockIdx.x * 256 + threadIdx.x;
    int w = n & 63, r = (n >> 6) & 63, b = n >> 12;

    float v[16];
#pragma unroll
    for (int c = 0; c < 16; ++c)
        v[c] = x[(((size_t)b * 16 + c) * 64 + r) * 64 + w];
    if (addflag) {
        const float* fp = fwd + (((size_t)b * 64 + r) * 64 + w) * 16;
#pragma unroll
        for (int c = 0; c < 16; ++c) v[c] += fp[c];
        if (r > 0) {
            const float* bp = bwdr + (((size_t)b * 64 + (r - 1)) * 64 + w) * 16;
#pragma unroll
            for (int c = 0; c < 16; ++c) v[c] += bp[c];
        }
#pragma unroll
        for (int c = 0; c < 16; ++c)
            x[(((size_t)b * 16 + c) * 64 + r) * 64 + w] = v[c];
    }

    const float4* wf4 = reinterpret_cast<const float4*>(wsh);
    const float4* wb4 = reinterpret_cast<const float4*>(wsh + 1024);
    float4* Gf = reinterpret_cast<float4*>(G + ((((size_t)b * 64 + r) * 64 + w) << 6));
    float4* Gb = reinterpret_cast<float4*>(G + (((((size_t)32 + b) * 64 + r) * 64 + (63 - w)) << 6));

#pragma unroll
    for (int c2 = 0; c2 < 16; ++c2) {
        float af[4], ab[4];
#pragma unroll
        for (int k = 0; k < 4; ++k) {
            int g = 16 * k + c2;
            float sf_ = 0.f, sb_ = 0.f;
#pragma unroll
            for (int c4 = 0; c4 < 4; ++c4) {
                float4 a = wf4[g * 4 + c4];
                float4 bq = wb4[g * 4 + c4];
                sf_ = fmaf(a.x, v[c4 * 4 + 0], sf_);
                sf_ = fmaf(a.y, v[c4 * 4 + 1], sf_);
                sf_ = fmaf(a.z, v[c4 * 4 + 2], sf_);
                sf_ = fmaf(a.w, v[c4 * 4 + 3], sf_);
                sb_ = fmaf(bq.x, v[c4 * 4 + 0], sb_);
                sb_ = fmaf(bq.y, v[c4 * 4 + 1], sb_);
                sb_ = fmaf(bq.z, v[c4 * 4 + 2], sb_);
                sb_ = fmaf(bq.w, v[c4 * 4 + 3], sb_);
            }
            af[k] = sf_; ab[k] = sb_;
        }
        float4 of_, ob_;
        of_.x = af[0]; of_.y = af[1]; of_.z = af[2]; of_.w = af[3];
        ob_.x = ab[0]; ob_.y = ab[1]; ob_.z = ab[2]; ob_.w = ab[3];
        Gf[c2] = of_;
        Gb[c2] = ob_;
    }
}

// ---------------- diagonal LSTM scan: one block per (b,dir) ----------------
// 512 threads: ch = t&15 (channel, handles gates ch,16+ch,32+ch,48+ch),
//              rp = t>>4 (row pair r0=2rp, r0+1). Single barrier per step,
//              double-buffered h in LDS, c-state + gate math in registers.
__global__ __launch_bounds__(512, 2) void k_scan(const float* __restrict__ G,
                                                 const float* __restrict__ w0_all,
                                                 const float* __restrict__ w1_all,
                                                 const float* __restrict__ bi_all,
                                                 int layer,
                                                 float* __restrict__ fwdbuf,
                                                 float* __restrict__ bwdbuf) {
    int dir = blockIdx.x >> 5, b = blockIdx.x & 31;
    int t = threadIdx.x;
    int ch = t & 15, rp = t >> 4;
    int r0 = rp * 2;
    int wb_ = (layer * 2 + dir) * 1024;

    float w1r[4][16], w0r[4][16], bir[4];
#pragma unroll
    for (int k = 0; k < 4; ++k) {
        int g = 16 * k + ch;
#pragma unroll
        for (int c = 0; c < 16; ++c) {
            w1r[k][c] = w1_all[wb_ + g * 16 + c];
            w0r[k][c] = w0_all[wb_ + g * 16 + c];
        }
        bir[k] = bi_all[(layer * 2 + dir) * 64 + g];
    }

    // h_lds[p][row_idx][c], row_idx 0 = guard (zeros), 1..64 = rows 0..63.
    // stride 20 floats: float4-aligned (80B), broadcast reads, conflict-light writes.
    __shared__ float h_lds[2][65][20];
    for (int i = t; i < 2 * 65 * 20; i += 512) (&h_lds[0][0][0])[i] = 0.f;

    const float* Gb = G + ((size_t)(dir * 32 + b) << 18);
    float* ob = dir ? bwdbuf : fwdbuf;
    const size_t obase = (size_t)b * 65536;

    float cst0 = 0.f, cst1 = 0.f;
    float4 gc0 = {0.f, 0.f, 0.f, 0.f}, gc1 = {0.f, 0.f, 0.f, 0.f};
    // prefetch for tt=0: w = 0 - r, valid only for r = 0
    if (r0 == 0) gc0 = *reinterpret_cast<const float4*>(Gb + ch * 4);
    __syncthreads();

    int p = 0;
#pragma unroll 1
    for (int tt = 0; tt < 127; ++tt) {
        // ---- prefetch G for step tt+1 (consumed next iteration) ----
        float4 gn0 = {0.f, 0.f, 0.f, 0.f}, gn1 = {0.f, 0.f, 0.f, 0.f};
        {
            int wa = tt + 1 - r0;
            if (wa >= 0 && wa < 64)
                gn0 = *reinterpret_cast<const float4*>(Gb + (((r0 << 6) + wa) << 6) + ch * 4);
            int wbb = wa - 1;
            if (wbb >= 0 && wbb < 64)
                gn1 = *reinterpret_cast<const float4*>(Gb + ((((r0 + 1) << 6) + wbb) << 6) + ch * 4);
        }

        // ---- s = bias + W1*h + W0*h_up for rows r0, r0+1 ----
        float s0[4], s1[4];
#pragma unroll
        for (int k = 0; k < 4; ++k) { s0[k] = bir[k]; s1[k] = bir[k]; }
        const float* hb = &h_lds[p][0][0];
#pragma unroll
        for (int c4 = 0; c4 < 4; ++c4) {
            float hm[4], h0[4], h1[4];
            *reinterpret_cast<float4*>(hm) = *reinterpret_cast<const float4*>(hb + r0 * 20 + c4 * 4);
            *reinterpret_cast<float4*>(h0) = *reinterpret_cast<const float4*>(hb + (r0 + 1) * 20 + c4 * 4);
            *reinterpret_cast<float4*>(h1) = *reinterpret_cast<const float4*>(hb + (r0 + 2) * 20 + c4 * 4);
#pragma unroll
            for (int j = 0; j < 4; ++j) {
                int c = c4 * 4 + j;
#pragma unroll
                for (int k = 0; k < 4; ++k) {
                    s0[k] = fmaf(w1r[k][c], h0[j], s0[k]);
                    s0[k] = fmaf(w0r[k][c], hm[j], s0[k]);
                    s1[k] = fmaf(w1r[k][c], h1[j], s1[k]);
                    s1[k] = fmaf(w0r[k][c], h0[j], s1[k]);
                }
            }
        }

        // ---- gates + state update, row r0 ----
        {
            float so = s0[0] + gc0.x, sf = s0[1] + gc0.y;
            float si = s0[2] + gc0.z, sg = s0[3] + gc0.w;
            float cn = fsig(sf) * cst0 + fsig(si) * ftanh(sg);
            cst0 = cn;
            float hn = fsig(so) * ftanh(cn);
            h_lds[p ^ 1][r0 + 1][ch] = hn;
            int w = tt - r0;
            if (w >= 0 && w < 64) {
                int wo = dir ? (63 - w) : w;
                ob[obase + ((size_t)((r0 << 6) + wo) << 4) + ch] = hn;
            }
        }
        // ---- gates + state update, row r0+1 ----
        {
            float so = s1[0] + gc1.x, sf = s1[1] + gc1.y;
            float si = s1[2] + gc1.z, sg = s1[3] + gc1.w;
            float cn = fsig(sf) * cst1 + fsig(si) * ftanh(sg);
            cst1 = cn;
            float hn = fsig(so) * ftanh(cn);
            h_lds[p ^ 1][r0 + 2][ch] = hn;
            int w = tt - r0 - 1;
            if (w >= 0 && w < 64) {
                int wo = dir ? (63 - w) : w;
                ob[obase + ((size_t)(((r0 + 1) << 6) + wo) << 4) + ch] = hn;
            }
        }
        gc0 = gn0; gc1 = gn1;

        // ---- single barrier: drain LDS writes only (NOT the global stores) ----
        asm volatile("s_waitcnt lgkmcnt(0)" ::: "memory");
        __builtin_amdgcn_sched_barrier(0);
        __builtin_amdgcn_s_barrier();
        __builtin_amdgcn_sched_barrier(0);
        p ^= 1;
    }
}

// ---------------- head: residual combine + 3-layer MLP ----------------
__global__ __launch_bounds__(256) void k_head(const float* __restrict__ x,
                                              const float* __restrict__ fwd,
                                              const float* __restrict__ bwdr,
                                              const float* __restrict__ W1,
                                              const float* __restrict__ B1,
                                              const float* __restrict__ W2,
                                              const float* __restrict__ B2,
                                              const float* __restrict__ W3,
                                              const float* __restrict__ B3,
                                              float* __restrict__ out) {
    int n = blockIdx.x * 256 + threadIdx.x;
    int w = n & 63, r = (n >> 6) & 63, b = n >> 12;
    float v[16];
    const float* fp = fwd + (((size_t)b * 64 + r) * 64 + w) * 16;
#pragma unroll
    for (int c = 0; c < 16; ++c)
        v[c] = x[(((size_t)b * 16 + c) * 64 + r) * 64 + w] + fp[c];
    if (r > 0) {
        const float* bp = bwdr + (((size_t)b * 64 + (r - 1)) * 64 + w) * 16;
#pragma unroll
        for (int c = 0; c < 16; ++c) v[c] += bp[c];
    }
    float h1[16];
#pragma unroll
    for (int o = 0; o < 16; ++o) {
        float a = B1[o];
#pragma unroll
        for (int c = 0; c < 16; ++c) a = fmaf(W1[o * 16 + c], v[c], a);
        h1[o] = fmaxf(a, 0.f);
    }
    float h2[16];
#pragma unroll
    for (int o = 0; o < 16; ++o) {
        float a = B2[o];
#pragma unroll
        for (int c = 0; c < 16; ++c) a = fmaf(W2[o * 16 + c], h1[c], a);
        h2[o] = fmaxf(a, 0.f);
    }
    float y = B3[0];
#pragma unroll
    for (int c = 0; c < 16; ++c) y = fmaf(W3[c], h2[c], y);
    out[((size_t)b * 64 + r) * 64 + w] = y;
}

extern "C" void kernel_launch(void* const* d_in, const int* in_sizes, int n_in,
                              void* d_out, int out_size, void* d_ws, size_t ws_size,
                              hipStream_t stream) {
    const float* X  = (const float*)d_in[0];
    const float* cw = (const float*)d_in[1];
    const float* cb = (const float*)d_in[2];
    const float* wi = (const float*)d_in[3];
    const float* bi = (const float*)d_in[4];
    const float* w0 = (const float*)d_in[5];
    const float* w1 = (const float*)d_in[6];
    const float* W1 = (const float*)d_in[7];
    const float* B1 = (const float*)d_in[8];
    const float* W2 = (const float*)d_in[9];
    const float* B2 = (const float*)d_in[10];
    const float* W3 = (const float*)d_in[11];
    const float* B3 = (const float*)d_in[12];
    float* out = (float*)d_out;

    char* ws = (char*)d_ws;
    float* x   = (float*)ws;                          //  8 MiB (32*16*64*64)
    float* fwd = (float*)(ws + ((size_t)8 << 20));    //  8 MiB
    float* bwd = (float*)(ws + ((size_t)16 << 20));   //  8 MiB
    float* G   = (float*)(ws + ((size_t)24 << 20));   // 64 MiB (2*32*64*64*64)

    k_conv<<<512, 256, 0, stream>>>(X, cw, cb, x);
    for (int l = 0; l < 7; ++l) {
        k_prep<<<512, 256, 0, stream>>>(x, fwd, bwd, wi, l, l > 0 ? 1 : 0, G);
        k_scan<<<64, 512, 0, stream>>>(G, w0, w1, bi, l, fwd, bwd);
    }
    k_head<<<512, 256, 0, stream>>>(x, fwd, bwd, W1, B1, W2, B2, W3, B3, out);
}

// Round 4
// 1201.298 us; speedup vs baseline: 4.1766x; 1.3858x over previous
//
#include <hip/hip_runtime.h>

#define DI __device__ __forceinline__

typedef __bf16 bf16x8 __attribute__((ext_vector_type(8)));
typedef float f32x4 __attribute__((ext_vector_type(4)));
typedef unsigned short u16x8 __attribute__((ext_vector_type(8)));
typedef unsigned short u16x4 __attribute__((ext_vector_type(4)));

DI float frcp(float x) { return __builtin_amdgcn_rcpf(x); }
DI float fsig(float x) { return frcp(1.0f + __expf(-x)); }
DI float ftanh(float x) { return 1.0f - 2.0f * frcp(1.0f + __expf(2.0f * x)); }

// ---------------- conv 7x7 masked, 1 -> 16 ch, pad 3; x out channel-last ----
__global__ __launch_bounds__(256) void k_conv(const float* __restrict__ X,
                                              const float* __restrict__ Wc,
                                              const float* __restrict__ Bc,
                                              float* __restrict__ xo) {
    int n = blockIdx.x * 256 + threadIdx.x;
    int xx = n & 63, yy = (n >> 6) & 63, b = n >> 12;
    float acc[16];
#pragma unroll
    for (int o = 0; o < 16; ++o) acc[o] = Bc[o];
    const float* Xb = X + (size_t)b * 4096;
#pragma unroll
    for (int ky = 0; ky < 4; ++ky) {
        int yi = yy + ky - 3;
        if (yi < 0) continue;
        int kxmax = (ky == 3) ? 3 : 7;
        for (int kx = 0; kx < kxmax; ++kx) {
            int xi = xx + kx - 3;
            if (xi < 0 || xi > 63) continue;
            float v = Xb[yi * 64 + xi];
#pragma unroll
            for (int o = 0; o < 16; ++o)
                acc[o] = fmaf(Wc[o * 49 + ky * 7 + kx], v, acc[o]);
        }
    }
    float4* xp = reinterpret_cast<float4*>(xo + (size_t)n * 16);
#pragma unroll
    for (int q = 0; q < 4; ++q) {
        float4 t; t.x = acc[q*4]; t.y = acc[q*4+1]; t.z = acc[q*4+2]; t.w = acc[q*4+3];
        xp[q] = t;
    }
}

// ---------------- prep: residual combine + i2s GEMV into f32 G --------------
// x: [b][r][w][16] f32. fwd/bwd: [b][r][w][16] f32 (bwd un-reversed).
// G (f32): [dir][b][r][c0g][w][16], element p = mb*4+reg holds gate
//   g = mb*16 + c0g*4 + reg at scan-coord w (reversed for dir=1).
__global__ __launch_bounds__(256) void k_prep(float* __restrict__ x,
                                              const float* __restrict__ fwd,
                                              const float* __restrict__ bwdr,
                                              const float* __restrict__ wi_all,
                                              int layer, int addflag,
                                              float* __restrict__ G) {
    __shared__ float wsh[2048];  // [dir][g][c]
    for (int i = threadIdx.x; i < 2048; i += 256)
        wsh[i] = wi_all[layer * 2048 + i];
    __syncthreads();

    int n = blockIdx.x * 256 + threadIdx.x;
    int w = n & 63, r = (n >> 6) & 63, b = n >> 12;
    size_t pix = (size_t)n;

    float v[16];
    const float4* xp = reinterpret_cast<const float4*>(x + pix * 16);
#pragma unroll
    for (int q = 0; q < 4; ++q) {
        float4 t = xp[q];
        v[q*4] = t.x; v[q*4+1] = t.y; v[q*4+2] = t.z; v[q*4+3] = t.w;
    }
    if (addflag) {
        const float4* fp = reinterpret_cast<const float4*>(fwd + pix * 16);
#pragma unroll
        for (int q = 0; q < 4; ++q) {
            float4 t = fp[q];
            v[q*4] += t.x; v[q*4+1] += t.y; v[q*4+2] += t.z; v[q*4+3] += t.w;
        }
        if (r > 0) {
            const float4* bp = reinterpret_cast<const float4*>(bwdr + (pix - 64) * 16);
#pragma unroll
            for (int q = 0; q < 4; ++q) {
                float4 t = bp[q];
                v[q*4] += t.x; v[q*4+1] += t.y; v[q*4+2] += t.z; v[q*4+3] += t.w;
            }
        }
        float4* xps = reinterpret_cast<float4*>(x + pix * 16);
#pragma unroll
        for (int q = 0; q < 4; ++q) {
            float4 t; t.x = v[q*4]; t.y = v[q*4+1]; t.z = v[q*4+2]; t.w = v[q*4+3];
            xps[q] = t;
        }
    }

#pragma unroll
    for (int dir = 0; dir < 2; ++dir) {
        const float* wp = wsh + dir * 1024;
        int wg = dir ? (63 - w) : w;
#pragma unroll
        for (int c0g = 0; c0g < 4; ++c0g) {
            float val[16];
#pragma unroll
            for (int mb = 0; mb < 4; ++mb) {
#pragma unroll
                for (int reg = 0; reg < 4; ++reg) {
                    int g = mb * 16 + c0g * 4 + reg;
                    const float4* wr = reinterpret_cast<const float4*>(wp + g * 16);
                    float s = 0.f;
#pragma unroll
                    for (int c4 = 0; c4 < 4; ++c4) {
                        float4 a = wr[c4];
                        s = fmaf(a.x, v[c4*4+0], s);
                        s = fmaf(a.y, v[c4*4+1], s);
                        s = fmaf(a.z, v[c4*4+2], s);
                        s = fmaf(a.w, v[c4*4+3], s);
                    }
                    val[mb * 4 + reg] = s;
                }
            }
            float4* dst = reinterpret_cast<float4*>(
                G + ((((size_t)(dir * 32 + b) * 64 + r) * 4 + c0g) * 64 + wg) * 16);
#pragma unroll
            for (int q = 0; q < 4; ++q) {
                float4 t; t.x = val[q*4]; t.y = val[q*4+1]; t.z = val[q*4+2]; t.w = val[q*4+3];
                dst[q] = t;
            }
        }
    }
}

// ---------------- diagonal LSTM scan via split-precision MFMA ---------------
// One block per (b,dir), 256 threads = 4 waves. Wave wv owns rows
// r = 16*wv + (lane&15); kb = lane>>4 = k-block AND channel group c0 = kb*4.
// h kept as bf16 hi+lo planes in LDS; W as bf16 hi+lo in registers.
// s = Whi*Hhi + Whi*Hlo + Wlo*Hhi  (~17 mantissa bits, fp32-equivalent here).
__global__ __launch_bounds__(256) void k_scan(const float* __restrict__ G,
                                              const float* __restrict__ w0_all,
                                              const float* __restrict__ w1_all,
                                              const float* __restrict__ bi_all,
                                              int layer,
                                              float* __restrict__ fwdbuf,
                                              float* __restrict__ bwdbuf) {
    int dir = blockIdx.x >> 5, b = blockIdx.x & 31;
    int t = threadIdx.x;
    int wv = t >> 6;
    int l = t & 63;
    int kb = l >> 4;
    int m = l & 15;
    int r = wv * 16 + m;
    int wb_ = (layer * 2 + dir) * 1024;

    // A fragments: A[g][k], k<16 -> W1[g][k], k>=16 -> W0[g][k-16].
    // lane kb holds k = kb*8..kb*8+7 (contiguous-k layout).
    const float* Wsel = (kb < 2 ? w1_all : w0_all) + wb_;
    int koff = (kb & 1) * 8;
    bf16x8 ahi[4], alo[4];
#pragma unroll
    for (int mb = 0; mb < 4; ++mb) {
        const float* wr = Wsel + (mb * 16 + m) * 16 + koff;
#pragma unroll
        for (int j = 0; j < 8; ++j) {
            float wv_ = wr[j];
            __bf16 hi = (__bf16)wv_;
            ahi[mb][j] = hi;
            alo[mb][j] = (__bf16)(wv_ - (float)hi);
        }
    }
    f32x4 biasv[4];
#pragma unroll
    for (int mb = 0; mb < 4; ++mb)
#pragma unroll
        for (int j = 0; j < 4; ++j)
            biasv[mb][j] = bi_all[(layer * 2 + dir) * 64 + mb * 16 + kb * 4 + j];

    // h double buffer x {hi,lo} planes, bf16 bits.
    // Row q holds image row q-1 (q=0 = zero guard). Stride 24 halfs (48B).
    __shared__ __align__(16) unsigned short hbuf[2][2][65 * 24];
    for (int i = t; i < 2 * 2 * 65 * 24; i += 256) (&hbuf[0][0][0])[i] = 0;

    const float* Glane = G + (((size_t)(dir * 32 + b) * 64 + r) * 4 + kb) * 1024;
    float* ob = dir ? bwdbuf : fwdbuf;
    const size_t obase = (size_t)b * 65536;

    float cst[4] = {0.f, 0.f, 0.f, 0.f};
    f32x4 gr[4];
#pragma unroll
    for (int q = 0; q < 4; ++q) gr[q] = (f32x4){0.f, 0.f, 0.f, 0.f};
    if (r == 0) {  // prefetch G for tt=0 (w=0 only valid at r=0)
        const f32x4* gp = reinterpret_cast<const f32x4*>(Glane);
#pragma unroll
        for (int q = 0; q < 4; ++q) gr[q] = gp[q];
    }
    __syncthreads();

    int p = 0;
#pragma unroll 1
    for (int tt = 0; tt < 127; ++tt) {
        // prefetch G for tt+1
        f32x4 nr[4];
#pragma unroll
        for (int q = 0; q < 4; ++q) nr[q] = (f32x4){0.f, 0.f, 0.f, 0.f};
        int wn = tt + 1 - r;
        if ((unsigned)wn < 64u) {
            const f32x4* gp = reinterpret_cast<const f32x4*>(Glane + (size_t)wn * 16);
#pragma unroll
            for (int q = 0; q < 4; ++q) nr[q] = gp[q];
        }

        // B fragments: kb0: h[r][ch0..7], kb1: h[r][ch8..15], kb2/3: h[r-1][..]
        int q = r + 1 - (kb >> 1);
        int boff = q * 24 + (kb & 1) * 8;
        u16x8 bh_raw = *reinterpret_cast<const u16x8*>(&hbuf[p][0][boff]);
        u16x8 bl_raw = *reinterpret_cast<const u16x8*>(&hbuf[p][1][boff]);
        bf16x8 bhi = __builtin_bit_cast(bf16x8, bh_raw);
        bf16x8 blo = __builtin_bit_cast(bf16x8, bl_raw);

        // acc init = bias + G, then split-precision MFMA accumulate
        f32x4 acc[4];
#pragma unroll
        for (int mb = 0; mb < 4; ++mb) acc[mb] = biasv[mb] + gr[mb];
#pragma unroll
        for (int mb = 0; mb < 4; ++mb)
            acc[mb] = __builtin_amdgcn_mfma_f32_16x16x32_bf16(ahi[mb], bhi, acc[mb], 0, 0, 0);
#pragma unroll
        for (int mb = 0; mb < 4; ++mb)
            acc[mb] = __builtin_amdgcn_mfma_f32_16x16x32_bf16(ahi[mb], blo, acc[mb], 0, 0, 0);
#pragma unroll
        for (int mb = 0; mb < 4; ++mb)
            acc[mb] = __builtin_amdgcn_mfma_f32_16x16x32_bf16(alo[mb], bhi, acc[mb], 0, 0, 0);

        // gates: lane holds (o,f,i,g) for channels ch = kb*4+j of row r
        int wcur = tt - r;
        bool vout = (unsigned)wcur < 64u;
        float hv[4];
        u16x4 hih, lol;
#pragma unroll
        for (int j = 0; j < 4; ++j) {
            float so = acc[0][j], sf = acc[1][j], si = acc[2][j], sg = acc[3][j];
            float cn = fsig(sf) * cst[j] + fsig(si) * ftanh(sg);
            cst[j] = cn;
            float hn = fsig(so) * ftanh(cn);
            hv[j] = hn;
            __bf16 hi = (__bf16)hn;
            hih[j] = __builtin_bit_cast(unsigned short, hi);
            lol[j] = __builtin_bit_cast(unsigned short, (__bf16)(hn - (float)hi));
        }
        int widx = (r + 1) * 24 + kb * 4;
        *reinterpret_cast<u16x4*>(&hbuf[p ^ 1][0][widx]) = hih;
        *reinterpret_cast<u16x4*>(&hbuf[p ^ 1][1][widx]) = lol;
        if (vout) {
            int wo = dir ? (63 - wcur) : wcur;
            float4 hq; hq.x = hv[0]; hq.y = hv[1]; hq.z = hv[2]; hq.w = hv[3];
            *reinterpret_cast<float4*>(ob + obase + ((size_t)((r << 6) + wo) << 4) + kb * 4) = hq;
        }
#pragma unroll
        for (int qq = 0; qq < 4; ++qq) gr[qq] = nr[qq];

        asm volatile("s_waitcnt lgkmcnt(0)" ::: "memory");
        __builtin_amdgcn_sched_barrier(0);
        __builtin_amdgcn_s_barrier();
        __builtin_amdgcn_sched_barrier(0);
        p ^= 1;
    }
}

// ---------------- head: residual combine + 3-layer MLP ----------------------
__global__ __launch_bounds__(256) void k_head(const float* __restrict__ x,
                                              const float* __restrict__ fwd,
                                              const float* __restrict__ bwdr,
                                              const float* __restrict__ W1,
                                              const float* __restrict__ B1,
                                              const float* __restrict__ W2,
                                              const float* __restrict__ B2,
                                              const float* __restrict__ W3,
                                              const float* __restrict__ B3,
                                              float* __restrict__ out) {
    int n = blockIdx.x * 256 + threadIdx.x;
    int r = (n >> 6) & 63;
    size_t pix = (size_t)n;
    float v[16];
    const float4* xp = reinterpret_cast<const float4*>(x + pix * 16);
#pragma unroll
    for (int q = 0; q < 4; ++q) {
        float4 t = xp[q];
        v[q*4] = t.x; v[q*4+1] = t.y; v[q*4+2] = t.z; v[q*4+3] = t.w;
    }
    const float4* fp = reinterpret_cast<const float4*>(fwd + pix * 16);
#pragma unroll
    for (int q = 0; q < 4; ++q) {
        float4 t = fp[q];
        v[q*4] += t.x; v[q*4+1] += t.y; v[q*4+2] += t.z; v[q*4+3] += t.w;
    }
    if (r > 0) {
        const float4* bp = reinterpret_cast<const float4*>(bwdr + (pix - 64) * 16);
#pragma unroll
        for (int q = 0; q < 4; ++q) {
            float4 t = bp[q];
            v[q*4] += t.x; v[q*4+1] += t.y; v[q*4+2] += t.z; v[q*4+3] += t.w;
        }
    }
    float h1[16];
#pragma unroll
    for (int o = 0; o < 16; ++o) {
        float a = B1[o];
#pragma unroll
        for (int c = 0; c < 16; ++c) a = fmaf(W1[o * 16 + c], v[c], a);
        h1[o] = fmaxf(a, 0.f);
    }
    float h2[16];
#pragma unroll
    for (int o = 0; o < 16; ++o) {
        float a = B2[o];
#pragma unroll
        for (int c = 0; c < 16; ++c) a = fmaf(W2[o * 16 + c], h1[c], a);
        h2[o] = fmaxf(a, 0.f);
    }
    float y = B3[0];
#pragma unroll
    for (int c = 0; c < 16; ++c) y = fmaf(W3[c], h2[c], y);
    out[pix] = y;
}

extern "C" void kernel_launch(void* const* d_in, const int* in_sizes, int n_in,
                              void* d_out, int out_size, void* d_ws, size_t ws_size,
                              hipStream_t stream) {
    const float* X  = (const float*)d_in[0];
    const float* cw = (const float*)d_in[1];
    const float* cb = (const float*)d_in[2];
    const float* wi = (const float*)d_in[3];
    const float* bi = (const float*)d_in[4];
    const float* w0 = (const float*)d_in[5];
    const float* w1 = (const float*)d_in[6];
    const float* W1 = (const float*)d_in[7];
    const float* B1 = (const float*)d_in[8];
    const float* W2 = (const float*)d_in[9];
    const float* B2 = (const float*)d_in[10];
    const float* W3 = (const float*)d_in[11];
    const float* B3 = (const float*)d_in[12];
    float* out = (float*)d_out;

    char* ws = (char*)d_ws;
    float* x   = (float*)ws;                          //  8 MiB f32 [b][r][w][16]
    float* fwd = (float*)(ws + ((size_t)8 << 20));    //  8 MiB f32
    float* bwd = (float*)(ws + ((size_t)16 << 20));   //  8 MiB f32
    float* G   = (float*)(ws + ((size_t)24 << 20));   // 64 MiB f32

    k_conv<<<512, 256, 0, stream>>>(X, cw, cb, x);
    for (int l = 0; l < 7; ++l) {
        k_prep<<<512, 256, 0, stream>>>(x, fwd, bwd, wi, l, l > 0 ? 1 : 0, G);
        k_scan<<<64, 256, 0, stream>>>(G, w0, w1, bi, l, fwd, bwd);
    }
    k_head<<<512, 256, 0, stream>>>(x, fwd, bwd, W1, B1, W2, B2, W3, B3, out);
}